// Round 5
// baseline (229.259 us; speedup 1.0000x reference)
//
#include <hip/hip_runtime.h>
#include <hip/hip_bf16.h>
#include <stdint.h>

typedef __bf16 bf16;
typedef __bf16 bf16x8 __attribute__((ext_vector_type(8)));
typedef __bf16 bf16x4 __attribute__((ext_vector_type(4)));
typedef short  s16x4  __attribute__((ext_vector_type(4)));
typedef short  s16x8  __attribute__((ext_vector_type(8)));
typedef float  f32x4  __attribute__((ext_vector_type(4)));

#define N_B 4
#define N_T 2048
#define N_D 768
#define N_H 12
#define N_DH 64
#define M_TOT (N_B * N_T)   // 8192

// async global->LDS, 16 bytes per lane. LDS dest must be base + lane*16.
__device__ __forceinline__ void async_copy16(const bf16* g, bf16* l) {
    __builtin_amdgcn_global_load_lds(
        (const __attribute__((address_space(1))) unsigned int*)g,
        (__attribute__((address_space(3))) unsigned int*)l,
        16, 0, 0);
}

// fused fp32 -> bf16 convert for three arrays (each size % 1024 == 0, so
// every 256-thread block stays within one segment)
__launch_bounds__(256)
__global__ void f2bf3(const float* __restrict__ a, bf16* __restrict__ oa, int na,
                      const float* __restrict__ b, bf16* __restrict__ ob, int nb,
                      const float* __restrict__ c, bf16* __restrict__ oc) {
    int i = (blockIdx.x * 256 + threadIdx.x) * 4;
    const float* src; bf16* dst;
    if (i < na)            { src = a; dst = oa; }
    else if (i < na + nb)  { src = b; dst = ob; i -= na; }
    else                   { src = c; dst = oc; i -= na + nb; }
    const float4 v = *(const float4*)(src + i);
    dst[i]     = (bf16)v.x;
    dst[i + 1] = (bf16)v.y;
    dst[i + 2] = (bf16)v.z;
    dst[i + 3] = (bf16)v.w;
}

// ---------------------------------------------------------------------------
// GEMM core: C[m,n] = sum_k A[m,k] * Bt[n,k]  (both K-contiguous, bf16)
// 128xTN tile, BK=32, 256 threads (4 waves, 2x2 of 64x(TN/2)), 16x16x32 MFMA.
// R4: DOUBLE-BUFFERED LDS, one barrier per k-step (attn-style schedule).
// The old schedule (sync; stage; sync; compute) drained vmcnt(0) right after
// issuing the loads -> full load latency exposed every k-step (GEMMs ran at
// ~310 TF vs the 874-912 TF this tile geometry achieves). Now tile t+1 is
// staged after the barrier while tile t computes; the barrier's implicit
// vmcnt(0) drain at the top of step t+1 waits on loads that had a full
// compute phase to land.
// ---------------------------------------------------------------------------
#define GEMM_STAGE(P, K0)                                                      \
    async_copy16(Ab + (K0), &lsA[P][t * 8]);                                   \
    async_copy16(Ab + (size_t)64 * KD + (K0), &lsA[P][2048 + t * 8]);          \
    async_copy16(Bb + (K0), &lsB[P][t * 8]);                                   \
    if (TN == 128) async_copy16(Bb + (size_t)64 * KD + (K0), &lsB[P][2048 + t * 8]);

#define GEMM_CORE(A_PTR, B_PTR, KDIM, TN_)                                     \
    constexpr int KD = (KDIM);                                                 \
    constexpr int TN = (TN_);                                                  \
    constexpr int JJ = TN / 32;                                                \
    constexpr int NT = KD / 32;                                                \
    __shared__ bf16 lsA[2][128 * 32];                                          \
    __shared__ bf16 lsB[2][TN * 32];                                           \
    const int m0 = blockIdx.x * 128;                                           \
    const int n0 = blockIdx.y * TN;                                            \
    const int t  = threadIdx.x;                                                \
    const int w  = t >> 6, l = t & 63;                                         \
    const int wm = w & 1, wn = w >> 1;                                         \
    const int lr = l & 15, lq = l >> 4;                                        \
    f32x4 acc[4][JJ] = {};                                                     \
    const bf16* Ab = (A_PTR) + (size_t)(m0 + (t >> 2)) * KD + (t & 3) * 8;     \
    const bf16* Bb = (B_PTR) + (size_t)(n0 + (t >> 2)) * KD + (t & 3) * 8;     \
    GEMM_STAGE(0, 0)                                                           \
    for (int t0 = 0; t0 < NT; t0++) {                                          \
        const int p = t0 & 1;                                                  \
        __syncthreads();                                                       \
        if (t0 + 1 < NT) { GEMM_STAGE(p ^ 1, (t0 + 1) * 32) }                  \
        bf16x8 af[4], bfr[JJ];                                                 \
        for (int i = 0; i < 4; i++)                                            \
            af[i] = *(const bf16x8*)(&lsA[p][(wm * 64 + i * 16 + lr) * 32 + lq * 8]); \
        for (int j = 0; j < JJ; j++)                                           \
            bfr[j] = *(const bf16x8*)(&lsB[p][(wn * (TN / 2) + j * 16 + lr) * 32 + lq * 8]); \
        for (int i = 0; i < 4; i++)                                            \
            for (int j = 0; j < JJ; j++)                                       \
                acc[i][j] = __builtin_amdgcn_mfma_f32_16x16x32_bf16(           \
                    af[i], bfr[j], acc[i][j], 0, 0, 0);                        \
    }

// QKV projection: Xb * Wb^T + b_qkv.
// Q: [B,H,T,64] pre-scaled by 0.125*log2(e) (softmax in base-2);
// K: [B,H,T,64]; V: transposed [B,H,64,T] with keys PERMUTED inside each
// 64-token tile so PV can run on 16x16x32 MFMA:
//   physical key p (ki=p>>4, lq=(p>>2)&3, r=p&3) lands at logical slot
//   s = 32*(ki&1) + 8*lq + 4*(ki>>1) + r
// which matches the x32 B-operand layout of the S^T C-layout output.
__launch_bounds__(256)
__global__ void gemm_qkv(const bf16* __restrict__ X, const bf16* __restrict__ W,
                         const float* __restrict__ bias,
                         bf16* __restrict__ Q, bf16* __restrict__ K,
                         bf16* __restrict__ Vt) {
    GEMM_CORE(X, W, 768, 128)
    // epilogue: C/D layout col=lane&15, row=(lane>>4)*4+reg
    for (int i = 0; i < 4; i++) {
        const int rowb = m0 + wm * 64 + i * 16 + lq * 4;
        const int b_ = rowb >> 11, tt = rowb & 2047;   // 128-tiles never straddle batch
        for (int j = 0; j < 4; j++) {
            const int col   = n0 + wn * 64 + j * 16 + lr;
            const int which = col / 768;
            const int rem   = col - which * 768;
            const int h     = rem >> 6, d = rem & 63;
            const float bv  = bias[col];
            if (which == 2) {
                // V^T with x32-friendly key permutation (tt multiple of 4 so
                // kl&3 = 0 at the base; r2 walks 4 consecutive slots)
                const int tile = tt >> 6, kl = tt & 63;
                const int ki = kl >> 4, lqv = (kl >> 2) & 3;
                const int idx = 32 * (ki & 1) + 8 * lqv + 4 * (ki >> 1);
                bf16x4 v4;
                for (int r2 = 0; r2 < 4; r2++) v4[r2] = (bf16)(acc[i][j][r2] + bv);
                *(bf16x4*)(Vt + ((size_t)((b_ * N_H + h) * 64 + d)) * 2048
                           + tile * 64 + idx) = v4;
            } else {
                bf16* dst = (which == 0) ? Q : K;
                const float sc = (which == 0) ? 0.18033688f : 1.0f;  // 1/8 * log2(e)
                for (int r2 = 0; r2 < 4; r2++)
                    dst[(size_t)(((b_ * N_H + h) << 11) + tt + r2) * 64 + d] =
                        (bf16)((acc[i][j][r2] + bv) * sc);
            }
        }
    }
}

// Output projection: Ob[8192x768] * Wpb[768x768]^T + b_proj -> out fp32
// TN=64 -> grid 64x12 = 768 blocks = exactly 3/CU (was 384 = 1.5/CU,
// 50% tail imbalance).
__launch_bounds__(256)
__global__ void gemm_proj(const bf16* __restrict__ O, const bf16* __restrict__ W,
                          const float* __restrict__ bias, float* __restrict__ out) {
    GEMM_CORE(O, W, 768, 64)
    for (int i = 0; i < 4; i++) {
        const int rowb = m0 + wm * 64 + i * 16 + lq * 4;
        for (int j = 0; j < JJ; j++) {
            const int col  = n0 + wn * (TN / 2) + j * 16 + lr;
            const float bv = bias[col];
            for (int r = 0; r < 4; r++)
                out[(size_t)(rowb + r) * 768 + col] = acc[i][j][r] + bv;
        }
    }
}

// ---------------------------------------------------------------------------
// Flash attention, 32-q-per-wave, ALL-x32 MFMA (unchanged from R3: 87.4us,
// conflicts 0, MfmaUtil 27, VALU~30 — latency-chain bound; attn levers are
// now smaller than the GEMM deficit, so R4 targets the GEMMs).
// Same algebra: S^T = K Q^T; O^T = V^T P^T; l via ones-MFMA;
// UNSHIFTED base-2 softmax: p = exp2(s), normalized once at the end.
// ---------------------------------------------------------------------------
__launch_bounds__(256, 3)
__global__ void attn(const bf16* __restrict__ Q, const bf16* __restrict__ K,
                     const bf16* __restrict__ Vt, bf16* __restrict__ O) {
    __shared__ bf16 lsK[2][64 * 64];
    __shared__ bf16 lsV[2][64 * 64];
    const int bid = blockIdx.x;
    const int xcd = bid & 7, slot = bid >> 3;
    const int bh  = xcd + 8 * (slot >> 4);   // 0..47, 6 heads per XCD
    const int qt  = slot & 15;               // 0..15
    const int t = threadIdx.x, w = t >> 6, l = t & 63;
    const int lr = l & 15, lq = l >> 4;
    const bf16* Qh  = Q  + (size_t)bh * N_T * 64;
    const bf16* Kh  = K  + (size_t)bh * N_T * 64;
    const bf16* Vth = Vt + (size_t)bh * 64 * N_T;
    const int q0 = qt * 128 + w * 32;        // this wave's q base (32 rows)

    // Q fragments for 2 q-groups (B-operand, n=q=lr, k=d)
    bf16x8 qf[2][2];
    #pragma unroll
    for (int qg = 0; qg < 2; qg++)
        #pragma unroll
        for (int ks = 0; ks < 2; ks++)
            qf[qg][ks] = *(const bf16x8*)(Qh + (size_t)(q0 + qg * 16 + lr) * 64
                                          + ks * 32 + lq * 8);

    f32x4 oacc[2][4] = {};                   // [qg] O^T[d = dj*16+lq*4+r][q=lr]
    f32x4 lacc[2]    = {};                   // [qg] l(q) via ones-MFMA
    const bf16x8 ones8 = {(bf16)1.f, (bf16)1.f, (bf16)1.f, (bf16)1.f,
                          (bf16)1.f, (bf16)1.f, (bf16)1.f, (bf16)1.f};

    // staging: 256 threads x 2 x 16B units per tile (K and V). XOR swizzle
    // on the source 16B unit matches the (row&7) XOR on the read side.
    // prologue: stage tile 0 into buffer 0
    #pragma unroll
    for (int j = 0; j < 2; j++) {
        const int u   = t + j * 256;         // 0..511
        const int row = u >> 3;              // 0..63
        const int scn = (u & 7) ^ (row & 7);
        async_copy16(Kh  + (size_t)row * 64 + scn * 8,   lsK[0] + u * 8);
        async_copy16(Vth + (size_t)row * 2048 + scn * 8, lsV[0] + u * 8);
    }

    for (int kt = 0; kt < 32; kt++) {
        const int cur = kt & 1;
        __syncthreads();   // drains buf[cur] copies; prev reads of buf[cur^1] done

        if (kt < 31) {     // prefetch next tile into the other buffer
            #pragma unroll
            for (int j = 0; j < 2; j++) {
                const int u   = t + j * 256;
                const int row = u >> 3;
                const int scn = (u & 7) ^ (row & 7);
                async_copy16(Kh + (size_t)((kt + 1) * 64 + row) * 64 + scn * 8,
                             lsK[cur ^ 1] + u * 8);
                async_copy16(Vth + (size_t)row * 2048 + (kt + 1) * 64 + scn * 8,
                             lsV[cur ^ 1] + u * 8);
            }
        }

        // ---- K fragments: read ONCE, reused across both q-groups ----
        bf16x8 kf[2][4];
        #pragma unroll
        for (int ks = 0; ks < 2; ks++)
            #pragma unroll
            for (int ki = 0; ki < 4; ki++) {
                const int row = ki * 16 + lr;
                kf[ks][ki] = *(const bf16x8*)(lsK[cur] + row * 64
                                              + ((ks * 4 + lq) ^ (lr & 7)) * 8);
            }

        // ---- S^T = K Q^T per q-group; p = exp2(s); pack bf16x8 for x32 ----
        bf16x8 pbf[2][2];                    // [qg][ks] B-operand of x32 PV
        #pragma unroll
        for (int qg = 0; qg < 2; qg++) {
            f32x4 sacc[4] = {};              // S^T[key = ki*16+lq*4+r][q=lr]
            __builtin_amdgcn_s_setprio(1);
            #pragma unroll
            for (int ks = 0; ks < 2; ks++)
                #pragma unroll
                for (int ki = 0; ki < 4; ki++)
                    sacc[ki] = __builtin_amdgcn_mfma_f32_16x16x32_bf16(
                        kf[ks][ki], qf[qg][ks], sacc[ki], 0, 0, 0);
            __builtin_amdgcn_s_setprio(0);
            // logical slot s(p)=32*(ki&1)+8*lq+4*(ki>>1)+r: ks-block ki&1,
            // j = 4*(ki>>1) + r  ->  pbf[ks] = {exp2 sacc[ks], exp2 sacc[ks+2]}
            #pragma unroll
            for (int ks = 0; ks < 2; ks++) {
                bf16x8 pb;
                #pragma unroll
                for (int r = 0; r < 4; r++) {
                    pb[r]     = (bf16)exp2f(sacc[ks][r]);
                    pb[4 + r] = (bf16)exp2f(sacc[ks + 2][r]);
                }
                pbf[qg][ks] = pb;
            }
        }

        // ---- O^T += V^T P^T (x32): V-frags read once, reused per qg ----
        __builtin_amdgcn_s_setprio(1);
        #pragma unroll
        for (int ks = 0; ks < 2; ks++)
            #pragma unroll
            for (int dj = 0; dj < 4; dj++) {
                const int row  = dj * 16 + lr;
                const int unit = (4 * ks + lq) ^ (lr & 7);
                bf16x8 vf = *(const bf16x8*)(lsV[cur] + row * 64 + unit * 8);
                #pragma unroll
                for (int qg = 0; qg < 2; qg++)
                    oacc[qg][dj] = __builtin_amdgcn_mfma_f32_16x16x32_bf16(
                        vf, pbf[qg][ks], oacc[qg][dj], 0, 0, 0);
            }
        // ---- l += 1 . P^T (matrix pipe, x32) ----
        #pragma unroll
        for (int qg = 0; qg < 2; qg++)
            #pragma unroll
            for (int ks = 0; ks < 2; ks++)
                lacc[qg] = __builtin_amdgcn_mfma_f32_16x16x32_bf16(
                    ones8, pbf[qg][ks], lacc[qg], 0, 0, 0);
        __builtin_amdgcn_s_setprio(0);
    }

    // ---- epilogue: O^T/l -> O [B,T,H*64] bf16, 8B packed stores ----
    const int b = bh / N_H, h = bh - b * N_H;
    #pragma unroll
    for (int qg = 0; qg < 2; qg++) {
        const float inv_l = 1.0f / lacc[qg][0];  // all 4 regs hold l(q=lr)
        const int tok = q0 + qg * 16 + lr;
        bf16* Ob = O + ((size_t)b * N_T + tok) * N_D + h * 64;
        #pragma unroll
        for (int dj = 0; dj < 4; dj++) {
            bf16x4 o4;
            #pragma unroll
            for (int r = 0; r < 4; r++) o4[r] = (bf16)(oacc[qg][dj][r] * inv_l);
            *(bf16x4*)(Ob + dj * 16 + lq * 4) = o4;
        }
    }
}

extern "C" void kernel_launch(void* const* d_in, const int* in_sizes, int n_in,
                              void* d_out, int out_size, void* d_ws, size_t ws_size,
                              hipStream_t stream) {
    const float* x      = (const float*)d_in[0];
    const float* W_qkv  = (const float*)d_in[1];
    const float* b_qkv  = (const float*)d_in[2];
    const float* W_proj = (const float*)d_in[3];
    const float* b_proj = (const float*)d_in[4];
    float* out = (float*)d_out;

    char* ws = (char*)d_ws;
    const size_t n_x  = (size_t)M_TOT * N_D;        // 6291456
    const size_t n_wq = (size_t)3 * N_D * N_D;      // 1769472
    const size_t n_wp = (size_t)N_D * N_D;          // 589824
    const size_t sz_qkv = (size_t)N_B * N_H * N_T * N_DH * sizeof(bf16);  // 12.58 MB

    bf16* xb  = (bf16*)(ws);                 ws += n_x * sizeof(bf16);
    bf16* Wqb = (bf16*)(ws);                 ws += n_wq * sizeof(bf16);
    bf16* Wpb = (bf16*)(ws);                 ws += n_wp * sizeof(bf16);
    bf16* Qb  = (bf16*)(ws);                 ws += sz_qkv;
    bf16* Kb  = (bf16*)(ws);                 ws += sz_qkv;
    bf16* Vtb = (bf16*)(ws);                 ws += sz_qkv;
    bf16* Ob  = (bf16*)(ws);

    dim3 blk(256);
    f2bf3<<<dim3((int)((n_x + n_wq + n_wp) / 1024)), blk, 0, stream>>>(
        x, xb, (int)n_x, W_qkv, Wqb, (int)n_wq, W_proj, Wpb);

    gemm_qkv<<<dim3(M_TOT / 128, 2304 / 128), blk, 0, stream>>>(xb, Wqb, b_qkv, Qb, Kb, Vtb);
    attn<<<dim3(768), dim3(256), 0, stream>>>(Qb, Kb, Vtb, Ob);
    gemm_proj<<<dim3(M_TOT / 128, 768 / 64), blk, 0, stream>>>(Ob, Wpb, b_proj, out);
}

// Round 6
// 221.050 us; speedup vs baseline: 1.0371x; 1.0371x over previous
//
#include <hip/hip_runtime.h>
#include <hip/hip_bf16.h>
#include <stdint.h>

typedef __bf16 bf16;
typedef __bf16 bf16x8 __attribute__((ext_vector_type(8)));
typedef __bf16 bf16x4 __attribute__((ext_vector_type(4)));
typedef short  s16x4  __attribute__((ext_vector_type(4)));
typedef short  s16x8  __attribute__((ext_vector_type(8)));
typedef float  f32x4  __attribute__((ext_vector_type(4)));

#define N_B 4
#define N_T 2048
#define N_D 768
#define N_H 12
#define N_DH 64
#define M_TOT (N_B * N_T)   // 8192

// async global->LDS, 16 bytes per lane. LDS dest must be base + lane*16.
__device__ __forceinline__ void async_copy16(const bf16* g, bf16* l) {
    __builtin_amdgcn_global_load_lds(
        (const __attribute__((address_space(1))) unsigned int*)g,
        (__attribute__((address_space(3))) unsigned int*)l,
        16, 0, 0);
}

// fused fp32 -> bf16 convert for three arrays (each size % 1024 == 0, so
// every 256-thread block stays within one segment)
__launch_bounds__(256)
__global__ void f2bf3(const float* __restrict__ a, bf16* __restrict__ oa, int na,
                      const float* __restrict__ b, bf16* __restrict__ ob, int nb,
                      const float* __restrict__ c, bf16* __restrict__ oc) {
    int i = (blockIdx.x * 256 + threadIdx.x) * 4;
    const float* src; bf16* dst;
    if (i < na)            { src = a; dst = oa; }
    else if (i < na + nb)  { src = b; dst = ob; i -= na; }
    else                   { src = c; dst = oc; i -= na + nb; }
    const float4 v = *(const float4*)(src + i);
    dst[i]     = (bf16)v.x;
    dst[i + 1] = (bf16)v.y;
    dst[i + 2] = (bf16)v.z;
    dst[i + 3] = (bf16)v.w;
}

// ---------------------------------------------------------------------------
// GEMM core: C[m,n] = sum_k A[m,k] * Bt[n,k]  (both K-contiguous, bf16)
// R6: rebuilt as the attn memory pattern (which measures 0 bank conflicts):
//  - BK=64, LDS tiles [row][64] bf16 (128B rows), XOR swizzle: 16B chunk c
//    of row r is stored at unit c^(r&7); fragment reads use the same XOR.
//    The old [row][32] layout was an 8-way conflict on every ds_read_b128
//    (classic row-major power-of-2 stride; m98 measured 1.7e7 conflicts on
//    this pattern) — ~3x effective LDS read cost.
//  - 12 k-steps instead of 24: 32 MFMAs/wave/barrier amortize the
//    stage+drain+barrier chain 2x better.
//  - double-buffered, 1 barrier per k-step, prefetch issued post-barrier.
// 128xTN tile, 256 threads (4 waves, 2x2 of 64x(TN/2)), 16x16x32 MFMA.
// LDS: TN=128 -> 64KB (2 blocks/CU); TN=64 -> 48KB (3 blocks/CU).
// ---------------------------------------------------------------------------
#define GEMM_STAGE(P, K0)                                                      \
    _Pragma("unroll")                                                          \
    for (int jj = 0; jj < 4; jj++)                                             \
        async_copy16(Ab + (size_t)jj * 32 * KD + (K0), &lsA[P][(jj * 256 + t) * 8]); \
    _Pragma("unroll")                                                          \
    for (int jj = 0; jj < TN / 32; jj++)                                       \
        async_copy16(Bb + (size_t)jj * 32 * KD + (K0), &lsB[P][(jj * 256 + t) * 8]);

#define GEMM_CORE(A_PTR, B_PTR, KDIM, TN_)                                     \
    constexpr int KD = (KDIM);                                                 \
    constexpr int TN = (TN_);                                                  \
    constexpr int JJ = TN / 32;                                                \
    constexpr int NT = KD / 64;                                                \
    __shared__ bf16 lsA[2][128 * 64];                                          \
    __shared__ bf16 lsB[2][TN * 64];                                           \
    const int m0 = blockIdx.x * 128;                                           \
    const int n0 = blockIdx.y * TN;                                            \
    const int t  = threadIdx.x;                                                \
    const int w  = t >> 6, l = t & 63;                                         \
    const int wm = w & 1, wn = w >> 1;                                         \
    const int lr = l & 15, lq = l >> 4;                                        \
    f32x4 acc[4][JJ] = {};                                                     \
    /* staging map: unit u = jj*256+t -> row = jj*32 + (t>>3), dest chunk     \
       t&7; source chunk cs = (t&7)^(row&7) = (t&7)^((t>>3)&7) (j-indep).  */ \
    const int cs = (t & 7) ^ ((t >> 3) & 7);                                   \
    const bf16* Ab = (A_PTR) + (size_t)(m0 + (t >> 3)) * KD + cs * 8;          \
    const bf16* Bb = (B_PTR) + (size_t)(n0 + (t >> 3)) * KD + cs * 8;          \
    GEMM_STAGE(0, 0)                                                           \
    for (int t0 = 0; t0 < NT; t0++) {                                          \
        const int p = t0 & 1;                                                  \
        __syncthreads();                                                       \
        if (t0 + 1 < NT) { GEMM_STAGE(p ^ 1, (t0 + 1) * 64) }                  \
        _Pragma("unroll")                                                      \
        for (int ks = 0; ks < 2; ks++) {                                       \
            bf16x8 af[4], bfr[JJ];                                             \
            _Pragma("unroll")                                                  \
            for (int i = 0; i < 4; i++)                                        \
                af[i] = *(const bf16x8*)(&lsA[p][(wm * 64 + i * 16 + lr) * 64  \
                                         + (((ks * 4 + lq) ^ (lr & 7)) * 8)]); \
            _Pragma("unroll")                                                  \
            for (int j = 0; j < JJ; j++)                                       \
                bfr[j] = *(const bf16x8*)(&lsB[p][(wn * (TN / 2) + j * 16 + lr) * 64 \
                                          + (((ks * 4 + lq) ^ (lr & 7)) * 8)]); \
            _Pragma("unroll")                                                  \
            for (int i = 0; i < 4; i++)                                        \
                _Pragma("unroll")                                              \
                for (int j = 0; j < JJ; j++)                                   \
                    acc[i][j] = __builtin_amdgcn_mfma_f32_16x16x32_bf16(       \
                        af[i], bfr[j], acc[i][j], 0, 0, 0);                    \
        }                                                                      \
    }

// QKV projection: Xb * Wb^T + b_qkv.
// Q: [B,H,T,64] pre-scaled by 0.125*log2(e) (softmax in base-2);
// K: [B,H,T,64]; V: transposed [B,H,64,T] with keys PERMUTED inside each
// 64-token tile so PV can run on 16x16x32 MFMA:
//   physical key p (ki=p>>4, lq=(p>>2)&3, r=p&3) lands at logical slot
//   s = 32*(ki&1) + 8*lq + 4*(ki>>1) + r
// which matches the x32 B-operand layout of the S^T C-layout output.
__launch_bounds__(256)
__global__ void gemm_qkv(const bf16* __restrict__ X, const bf16* __restrict__ W,
                         const float* __restrict__ bias,
                         bf16* __restrict__ Q, bf16* __restrict__ K,
                         bf16* __restrict__ Vt) {
    GEMM_CORE(X, W, 768, 128)
    // epilogue: C/D layout col=lane&15, row=(lane>>4)*4+reg
    for (int i = 0; i < 4; i++) {
        const int rowb = m0 + wm * 64 + i * 16 + lq * 4;
        const int b_ = rowb >> 11, tt = rowb & 2047;   // 128-tiles never straddle batch
        for (int j = 0; j < 4; j++) {
            const int col   = n0 + wn * 64 + j * 16 + lr;
            const int which = col / 768;
            const int rem   = col - which * 768;
            const int h     = rem >> 6, d = rem & 63;
            const float bv  = bias[col];
            if (which == 2) {
                // V^T with x32-friendly key permutation (tt multiple of 4 so
                // kl&3 = 0 at the base; r2 walks 4 consecutive slots)
                const int tile = tt >> 6, kl = tt & 63;
                const int ki = kl >> 4, lqv = (kl >> 2) & 3;
                const int idx = 32 * (ki & 1) + 8 * lqv + 4 * (ki >> 1);
                bf16x4 v4;
                for (int r2 = 0; r2 < 4; r2++) v4[r2] = (bf16)(acc[i][j][r2] + bv);
                *(bf16x4*)(Vt + ((size_t)((b_ * N_H + h) * 64 + d)) * 2048
                           + tile * 64 + idx) = v4;
            } else {
                bf16* dst = (which == 0) ? Q : K;
                const float sc = (which == 0) ? 0.18033688f : 1.0f;  // 1/8 * log2(e)
                for (int r2 = 0; r2 < 4; r2++)
                    dst[(size_t)(((b_ * N_H + h) << 11) + tt + r2) * 64 + d] =
                        (bf16)((acc[i][j][r2] + bv) * sc);
            }
        }
    }
}

// Output projection: Ob[8192x768] * Wpb[768x768]^T + b_proj -> out fp32
// TN=64 -> grid 64x12 = 768 blocks = exactly 3/CU; 48KB LDS -> 3 blocks/CU.
__launch_bounds__(256)
__global__ void gemm_proj(const bf16* __restrict__ O, const bf16* __restrict__ W,
                          const float* __restrict__ bias, float* __restrict__ out) {
    GEMM_CORE(O, W, 768, 64)
    for (int i = 0; i < 4; i++) {
        const int rowb = m0 + wm * 64 + i * 16 + lq * 4;
        for (int j = 0; j < JJ; j++) {
            const int col  = n0 + wn * (TN / 2) + j * 16 + lr;
            const float bv = bias[col];
            for (int r = 0; r < 4; r++)
                out[(size_t)(rowb + r) * 768 + col] = acc[i][j][r] + bv;
        }
    }
}

// ---------------------------------------------------------------------------
// Flash attention, 32-q-per-wave, ALL-x32 MFMA (unchanged from R3: ~88us,
// conflicts 0, MfmaUtil 27 — latency-chain bound; GEMMs carry more absolute
// headroom, so R6 targets the GEMMs).
// Same algebra: S^T = K Q^T; O^T = V^T P^T; l via ones-MFMA;
// UNSHIFTED base-2 softmax: p = exp2(s), normalized once at the end.
// ---------------------------------------------------------------------------
__launch_bounds__(256, 3)
__global__ void attn(const bf16* __restrict__ Q, const bf16* __restrict__ K,
                     const bf16* __restrict__ Vt, bf16* __restrict__ O) {
    __shared__ bf16 lsK[2][64 * 64];
    __shared__ bf16 lsV[2][64 * 64];
    const int bid = blockIdx.x;
    const int xcd = bid & 7, slot = bid >> 3;
    const int bh  = xcd + 8 * (slot >> 4);   // 0..47, 6 heads per XCD
    const int qt  = slot & 15;               // 0..15
    const int t = threadIdx.x, w = t >> 6, l = t & 63;
    const int lr = l & 15, lq = l >> 4;
    const bf16* Qh  = Q  + (size_t)bh * N_T * 64;
    const bf16* Kh  = K  + (size_t)bh * N_T * 64;
    const bf16* Vth = Vt + (size_t)bh * 64 * N_T;
    const int q0 = qt * 128 + w * 32;        // this wave's q base (32 rows)

    // Q fragments for 2 q-groups (B-operand, n=q=lr, k=d)
    bf16x8 qf[2][2];
    #pragma unroll
    for (int qg = 0; qg < 2; qg++)
        #pragma unroll
        for (int ks = 0; ks < 2; ks++)
            qf[qg][ks] = *(const bf16x8*)(Qh + (size_t)(q0 + qg * 16 + lr) * 64
                                          + ks * 32 + lq * 8);

    f32x4 oacc[2][4] = {};                   // [qg] O^T[d = dj*16+lq*4+r][q=lr]
    f32x4 lacc[2]    = {};                   // [qg] l(q) via ones-MFMA
    const bf16x8 ones8 = {(bf16)1.f, (bf16)1.f, (bf16)1.f, (bf16)1.f,
                          (bf16)1.f, (bf16)1.f, (bf16)1.f, (bf16)1.f};

    // staging: 256 threads x 2 x 16B units per tile (K and V). XOR swizzle
    // on the source 16B unit matches the (row&7) XOR on the read side.
    // prologue: stage tile 0 into buffer 0
    #pragma unroll
    for (int j = 0; j < 2; j++) {
        const int u   = t + j * 256;         // 0..511
        const int row = u >> 3;              // 0..63
        const int scn = (u & 7) ^ (row & 7);
        async_copy16(Kh  + (size_t)row * 64 + scn * 8,   lsK[0] + u * 8);
        async_copy16(Vth + (size_t)row * 2048 + scn * 8, lsV[0] + u * 8);
    }

    for (int kt = 0; kt < 32; kt++) {
        const int cur = kt & 1;
        __syncthreads();   // drains buf[cur] copies; prev reads of buf[cur^1] done

        if (kt < 31) {     // prefetch next tile into the other buffer
            #pragma unroll
            for (int j = 0; j < 2; j++) {
                const int u   = t + j * 256;
                const int row = u >> 3;
                const int scn = (u & 7) ^ (row & 7);
                async_copy16(Kh + (size_t)((kt + 1) * 64 + row) * 64 + scn * 8,
                             lsK[cur ^ 1] + u * 8);
                async_copy16(Vth + (size_t)row * 2048 + (kt + 1) * 64 + scn * 8,
                             lsV[cur ^ 1] + u * 8);
            }
        }

        // ---- K fragments: read ONCE, reused across both q-groups ----
        bf16x8 kf[2][4];
        #pragma unroll
        for (int ks = 0; ks < 2; ks++)
            #pragma unroll
            for (int ki = 0; ki < 4; ki++) {
                const int row = ki * 16 + lr;
                kf[ks][ki] = *(const bf16x8*)(lsK[cur] + row * 64
                                              + ((ks * 4 + lq) ^ (lr & 7)) * 8);
            }

        // ---- S^T = K Q^T per q-group; p = exp2(s); pack bf16x8 for x32 ----
        bf16x8 pbf[2][2];                    // [qg][ks] B-operand of x32 PV
        #pragma unroll
        for (int qg = 0; qg < 2; qg++) {
            f32x4 sacc[4] = {};              // S^T[key = ki*16+lq*4+r][q=lr]
            __builtin_amdgcn_s_setprio(1);
            #pragma unroll
            for (int ks = 0; ks < 2; ks++)
                #pragma unroll
                for (int ki = 0; ki < 4; ki++)
                    sacc[ki] = __builtin_amdgcn_mfma_f32_16x16x32_bf16(
                        kf[ks][ki], qf[qg][ks], sacc[ki], 0, 0, 0);
            __builtin_amdgcn_s_setprio(0);
            // logical slot s(p)=32*(ki&1)+8*lq+4*(ki>>1)+r: ks-block ki&1,
            // j = 4*(ki>>1) + r  ->  pbf[ks] = {exp2 sacc[ks], exp2 sacc[ks+2]}
            #pragma unroll
            for (int ks = 0; ks < 2; ks++) {
                bf16x8 pb;
                #pragma unroll
                for (int r = 0; r < 4; r++) {
                    pb[r]     = (bf16)exp2f(sacc[ks][r]);
                    pb[4 + r] = (bf16)exp2f(sacc[ks + 2][r]);
                }
                pbf[qg][ks] = pb;
            }
        }

        // ---- O^T += V^T P^T (x32): V-frags read once, reused per qg ----
        __builtin_amdgcn_s_setprio(1);
        #pragma unroll
        for (int ks = 0; ks < 2; ks++)
            #pragma unroll
            for (int dj = 0; dj < 4; dj++) {
                const int row  = dj * 16 + lr;
                const int unit = (4 * ks + lq) ^ (lr & 7);
                bf16x8 vf = *(const bf16x8*)(lsV[cur] + row * 64 + unit * 8);
                #pragma unroll
                for (int qg = 0; qg < 2; qg++)
                    oacc[qg][dj] = __builtin_amdgcn_mfma_f32_16x16x32_bf16(
                        vf, pbf[qg][ks], oacc[qg][dj], 0, 0, 0);
            }
        // ---- l += 1 . P^T (matrix pipe, x32) ----
        #pragma unroll
        for (int qg = 0; qg < 2; qg++)
            #pragma unroll
            for (int ks = 0; ks < 2; ks++)
                lacc[qg] = __builtin_amdgcn_mfma_f32_16x16x32_bf16(
                    ones8, pbf[qg][ks], lacc[qg], 0, 0, 0);
        __builtin_amdgcn_s_setprio(0);
    }

    // ---- epilogue: O^T/l -> O [B,T,H*64] bf16, 8B packed stores ----
    const int b = bh / N_H, h = bh - b * N_H;
    #pragma unroll
    for (int qg = 0; qg < 2; qg++) {
        const float inv_l = 1.0f / lacc[qg][0];  // all 4 regs hold l(q=lr)
        const int tok = q0 + qg * 16 + lr;
        bf16* Ob = O + ((size_t)b * N_T + tok) * N_D + h * 64;
        #pragma unroll
        for (int dj = 0; dj < 4; dj++) {
            bf16x4 o4;
            #pragma unroll
            for (int r = 0; r < 4; r++) o4[r] = (bf16)(oacc[qg][dj][r] * inv_l);
            *(bf16x4*)(Ob + dj * 16 + lq * 4) = o4;
        }
    }
}

extern "C" void kernel_launch(void* const* d_in, const int* in_sizes, int n_in,
                              void* d_out, int out_size, void* d_ws, size_t ws_size,
                              hipStream_t stream) {
    const float* x      = (const float*)d_in[0];
    const float* W_qkv  = (const float*)d_in[1];
    const float* b_qkv  = (const float*)d_in[2];
    const float* W_proj = (const float*)d_in[3];
    const float* b_proj = (const float*)d_in[4];
    float* out = (float*)d_out;

    char* ws = (char*)d_ws;
    const size_t n_x  = (size_t)M_TOT * N_D;        // 6291456
    const size_t n_wq = (size_t)3 * N_D * N_D;      // 1769472
    const size_t n_wp = (size_t)N_D * N_D;          // 589824
    const size_t sz_qkv = (size_t)N_B * N_H * N_T * N_DH * sizeof(bf16);  // 12.58 MB

    bf16* xb  = (bf16*)(ws);                 ws += n_x * sizeof(bf16);
    bf16* Wqb = (bf16*)(ws);                 ws += n_wq * sizeof(bf16);
    bf16* Wpb = (bf16*)(ws);                 ws += n_wp * sizeof(bf16);
    bf16* Qb  = (bf16*)(ws);                 ws += sz_qkv;
    bf16* Kb  = (bf16*)(ws);                 ws += sz_qkv;
    bf16* Vtb = (bf16*)(ws);                 ws += sz_qkv;
    bf16* Ob  = (bf16*)(ws);

    dim3 blk(256);
    f2bf3<<<dim3((int)((n_x + n_wq + n_wp) / 1024)), blk, 0, stream>>>(
        x, xb, (int)n_x, W_qkv, Wqb, (int)n_wq, W_proj, Wpb);

    gemm_qkv<<<dim3(M_TOT / 128, 2304 / 128), blk, 0, stream>>>(xb, Wqb, b_qkv, Qb, Kb, Vtb);
    attn<<<dim3(768), dim3(256), 0, stream>>>(Qb, Kb, Vtb, Ob);
    gemm_proj<<<dim3(M_TOT / 128, 768 / 64), blk, 0, stream>>>(Ob, Wpb, b_proj, out);
}